// Round 8
// baseline (1448.535 us; speedup 1.0000x reference)
//
#include <hip/hip_runtime.h>
#include <hip/hip_bf16.h>

#define SEQ 256
#define NB 16
#define HID 512
#define VOC 32000

typedef short bf16x8 __attribute__((ext_vector_type(8)));
typedef float f32x4 __attribute__((ext_vector_type(4)));
typedef unsigned long long u64;

__device__ __forceinline__ void ld_lds16(const void* g, void* l) {
  __builtin_amdgcn_global_load_lds((const __attribute__((address_space(1))) void*)g,
                                   (__attribute__((address_space(3))) void*)l, 16, 0, 0);
}

__device__ __forceinline__ float sigf(float x) { return 1.0f / (1.0f + expf(-x)); }

__device__ __forceinline__ unsigned pk2(float a, float b) {
  __hip_bfloat16 ha = __float2bfloat16(a), hb = __float2bfloat16(b);
  unsigned short ua = *(unsigned short*)&ha, ub = *(unsigned short*)&hb;
  return (unsigned)ua | ((unsigned)ub << 16);
}

__device__ __forceinline__ u64 agload(const u64* p) {
  return __hip_atomic_load(p, __ATOMIC_RELAXED, __HIP_MEMORY_SCOPE_AGENT);
}
__device__ __forceinline__ void agstore(u64* p, u64 v) {
  __hip_atomic_store(p, v, __ATOMIC_RELAXED, __HIP_MEMORY_SCOPE_AGENT);
}

// 16 staging u64s per lane: chunk s (0..3), j (0..3); addr = base + s*256 + j*16 (u64 units)
__device__ __forceinline__ void issue16(u64* q, const u64* base) {
#pragma unroll
  for (int s = 0; s < 4; ++s)
#pragma unroll
    for (int j = 0; j < 4; ++j) q[s * 4 + j] = agload(base + s * 256 + j * 16);
}

// Sentinel-first revalidate: poll only q[0] (512B/wave/round) until fresh, then full rounds.
__device__ __forceinline__ void revalidate16(u64* q, const u64* base, unsigned tg) {
  for (;;) {  // phase 1: sentinel
    bool ok = ((unsigned)(q[0] >> 32) == tg);
    if (__all(ok)) break;
    __builtin_amdgcn_s_sleep(2);
    if (!ok) q[0] = agload(base);
  }
  for (;;) {  // phase 2: remaining 15
    int bad = 0;
#pragma unroll
    for (int i = 1; i < 16; ++i) bad |= ((unsigned)(q[i] >> 32) != tg);
    if (!__any(bad)) break;
    __builtin_amdgcn_s_sleep(1);
#pragma unroll
    for (int i = 1; i < 16; ++i)
      if ((unsigned)(q[i] >> 32) != tg)
        q[i] = agload(base + (i >> 2) * 256 + (i & 3) * 16);
  }
}

// 8 f32 -> bf16 hi + bf16 lo(residual) vectors
__device__ __forceinline__ void cvt8_hilo(const float* p, bf16x8* h8, bf16x8* l8) {
  union { unsigned short u[8]; bf16x8 v; } uh, ul;
#pragma unroll
  for (int i = 0; i < 8; ++i) {
    float v = p[i];
    __hip_bfloat16 h = __float2bfloat16(v);
    uh.u[i] = *(unsigned short*)&h;
    float rem = v - __bfloat162float(h);
    __hip_bfloat16 l = __float2bfloat16(rem);
    ul.u[i] = *(unsigned short*)&l;
  }
  *h8 = uh.v;
  *l8 = ul.v;
}

// ---------------- embedding gather -> bf16, xe[t*16+b][512] ----------------
__global__ void embed_k(const int* __restrict__ x, const float* __restrict__ emb,
                        unsigned short* __restrict__ xe) {
  int bid = blockIdx.x;  // = t*16 + b
  int t = bid >> 4, b = bid & 15;
  int tok = x[b * SEQ + t];
  const float4* src = (const float4*)(emb + (size_t)tok * HID);
  int e = threadIdx.x;
  float4 a = src[e * 2], c = src[e * 2 + 1];
  uint4 o;
  o.x = pk2(a.x, a.y); o.y = pk2(a.z, a.w);
  o.z = pk2(c.x, c.y); o.w = pk2(c.z, c.w);
  ((uint4*)(xe + (size_t)bid * HID))[e] = o;
}

// ---------------- f32 -> bf16 pack, 8/thread ----------------
__global__ void cvt_k(const float* __restrict__ in, uint4* __restrict__ out) {
  size_t i = (size_t)blockIdx.x * blockDim.x + threadIdx.x;
  const float4* in4 = (const float4*)in;
  float4 a = in4[i * 2], b = in4[i * 2 + 1];
  uint4 o;
  o.x = pk2(a.x, a.y); o.y = pk2(a.z, a.w);
  o.z = pk2(b.x, b.y); o.w = pk2(b.z, b.w);
  out[i] = o;
}

// ---------------- gx GEMM: gx[4096][2048] bf16 = xe @ Wih0^T ----------------
__global__ __launch_bounds__(256) void gx_gemm(const __hip_bfloat16* __restrict__ A,
                                               const __hip_bfloat16* __restrict__ Bw,
                                               unsigned short* __restrict__ C) {
  __shared__ __align__(16) unsigned short lds_a[128 * 32];
  __shared__ __align__(16) unsigned short lds_b[128 * 32];
  const int tid = threadIdx.x;
  const int lane = tid & 63, wid = tid >> 6;
  const int m0 = blockIdx.y * 128, n0 = blockIdx.x * 128;
  const char* Ab = (const char*)A;
  const char* Bb = (const char*)Bw;
  const int ra = tid >> 2, cb = (tid & 3) * 16;
  f32x4 acc[4][4] = {};
  const int wm = (wid >> 1) * 64, wn = (wid & 1) * 64;
  const int fr = lane & 15, fk = (lane >> 4) * 8;
  for (int k0 = 0; k0 < HID; k0 += 32) {
    ld_lds16(Ab + (size_t)(m0 + ra) * 1024 + k0 * 2 + cb, (char*)lds_a + wid * 1024);
    ld_lds16(Ab + (size_t)(m0 + 64 + ra) * 1024 + k0 * 2 + cb, (char*)lds_a + 4096 + wid * 1024);
    ld_lds16(Bb + (size_t)(n0 + ra) * 1024 + k0 * 2 + cb, (char*)lds_b + wid * 1024);
    ld_lds16(Bb + (size_t)(n0 + 64 + ra) * 1024 + k0 * 2 + cb, (char*)lds_b + 4096 + wid * 1024);
    __syncthreads();
    bf16x8 af[4], bf[4];
#pragma unroll
    for (int i = 0; i < 4; ++i) af[i] = *(const bf16x8*)&lds_a[(wm + i * 16 + fr) * 32 + fk];
#pragma unroll
    for (int j = 0; j < 4; ++j) bf[j] = *(const bf16x8*)&lds_b[(wn + j * 16 + fr) * 32 + fk];
#pragma unroll
    for (int i = 0; i < 4; ++i)
#pragma unroll
      for (int j = 0; j < 4; ++j)
        acc[i][j] = __builtin_amdgcn_mfma_f32_16x16x32_bf16(af[i], bf[j], acc[i][j], 0, 0, 0);
    __syncthreads();
  }
  const int cr = (lane >> 4) * 4, cc = lane & 15;
#pragma unroll
  for (int i = 0; i < 4; ++i)
#pragma unroll
    for (int jj = 0; jj < 4; ++jj) {
      size_t base = (size_t)(m0 + wm + i * 16 + cr) * 2048 + (n0 + wn + jj * 16 + cc);
#pragma unroll
      for (int r = 0; r < 4; ++r) {
        __hip_bfloat16 h = __float2bfloat16(acc[i][jj][r]);
        C[base + (size_t)r * 2048] = *(unsigned short*)&h;
      }
    }
}

// ---------------- persistent LSTM: 128 blocks x 4 waves, 8 cols/block ----------------
// lay = bid>>6, r = bid&63: 32 gate rows = 2 MFMA row-tiles (tile m: cols hc0+m*4..+3, 4 gates).
// Wave wid owns k-slice [wid*128,+128). B-frags shared across tiles -> same poll traffic,
// half the polling blocks vs round 7. Weights in regs (bf16 hi/lo). Sentinel-first polling.
__global__ __launch_bounds__(256, 1) void lstm_k(
    const float* __restrict__ Wih, const float* __restrict__ Whh,
    const float* __restrict__ bias, const unsigned short* __restrict__ gxb,
    u64* __restrict__ h0r, u64* __restrict__ h1r, unsigned short* __restrict__ outs) {
  __shared__ float pbuf[4][32][17];
  const int tid = threadIdx.x, bid = blockIdx.x;
  const int lay = bid >> 6, r = bid & 63;
  const int hc0 = r * 8;
  const int wid = tid >> 6, lane = tid & 63;
  const int b16 = lane & 15, hi = lane >> 4;

  // ---- weights -> registers: A-row b16 of tile m: jrow = (b16>>2)*512 + hc0 + m*4 + (b16&3)
  const int kb = wid * 128 + hi * 8;
  bf16x8 Wh[2][2][4], Wi[2][2][4];  // [tile][hi/lo][s]; lay0 uses Wh only
#pragma unroll
  for (int m = 0; m < 2; ++m) {
    const int jrow = (b16 >> 2) * HID + hc0 + m * 4 + (b16 & 3);
    const float* whh_row = Whh + ((size_t)lay * 2048 + jrow) * HID;
    const float* wih_row = Wih + ((size_t)lay * 2048 + jrow) * HID;
#pragma unroll
    for (int s = 0; s < 4; ++s) {
      cvt8_hilo(whh_row + kb + s * 32, &Wh[m][0][s], &Wh[m][1][s]);
      if (lay) cvt8_hilo(wih_row + kb + s * 32, &Wi[m][0][s], &Wi[m][1][s]);
      else { Wi[m][0][s] = Wh[m][0][s]; Wi[m][1][s] = Wh[m][1][s]; }
    }
  }
  const int eb = lane & 15, ehl = lane >> 4;  // epilogue map (wave0): batch, local col 0..3
  float bq[2][4];
#pragma unroll
  for (int m = 0; m < 2; ++m)
#pragma unroll
    for (int q = 0; q < 4; ++q)
      bq[m][q] = bias[lay * 2048 + q * HID + hc0 + m * 4 + ehl];
  float c0 = 0.f, c1 = 0.f;
  const int lbase = wid * 1024 + hi * 64 + b16;  // u64 index within 4096-u64 slot

#pragma unroll 1
  for (int t = 0; t < SEQ; ++t) {
    f32x4 ah0 = {0.f, 0.f, 0.f, 0.f}, al0 = {0.f, 0.f, 0.f, 0.f};
    f32x4 ah1 = {0.f, 0.f, 0.f, 0.f}, al1 = {0.f, 0.f, 0.f, 0.f};
    float gxr[2][4] = {};
    if (lay == 0) {
      const u64* srcA = h0r + (size_t)t * 4096 + lbase;  // h0[t-1], tag t
      u64 qa[16];
      issue16(qa, srcA);
      if (wid == 0) {
        const unsigned short* gp = gxb + ((size_t)(t * 16 + eb)) * 2048 + hc0 + ehl;
#pragma unroll
        for (int m = 0; m < 2; ++m)
#pragma unroll
          for (int q = 0; q < 4; ++q) {
            union { unsigned u; float f; } cv;
            cv.u = (unsigned)gp[m * 4 + q * HID] << 16;
            gxr[m][q] = cv.f;
            asm volatile("" : "+v"(gxr[m][q]));
          }
      }
      revalidate16(qa, srcA, (unsigned)t);
#pragma unroll
      for (int s = 0; s < 4; ++s) {
        union { unsigned u[4]; bf16x8 v; } bb;
#pragma unroll
        for (int j = 0; j < 4; ++j) bb.u[j] = (unsigned)qa[s * 4 + j];
        ah0 = __builtin_amdgcn_mfma_f32_16x16x32_bf16(Wh[0][0][s], bb.v, ah0, 0, 0, 0);
        al0 = __builtin_amdgcn_mfma_f32_16x16x32_bf16(Wh[0][1][s], bb.v, al0, 0, 0, 0);
        ah1 = __builtin_amdgcn_mfma_f32_16x16x32_bf16(Wh[1][0][s], bb.v, ah1, 0, 0, 0);
        al1 = __builtin_amdgcn_mfma_f32_16x16x32_bf16(Wh[1][1][s], bb.v, al1, 0, 0, 0);
      }
    } else {
      const u64* srcA = h0r + (size_t)(t + 1) * 4096 + lbase;  // h0[t], tag t+1
      const u64* srcB = h1r + (size_t)t * 4096 + lbase;        // h1[t-1], tag t
      u64 qb[16], qa[16];
      issue16(qb, srcB);
      issue16(qa, srcA);
      revalidate16(qb, srcB, (unsigned)t);
#pragma unroll
      for (int s = 0; s < 4; ++s) {
        union { unsigned u[4]; bf16x8 v; } bb;
#pragma unroll
        for (int j = 0; j < 4; ++j) bb.u[j] = (unsigned)qb[s * 4 + j];
        ah0 = __builtin_amdgcn_mfma_f32_16x16x32_bf16(Wh[0][0][s], bb.v, ah0, 0, 0, 0);
        al0 = __builtin_amdgcn_mfma_f32_16x16x32_bf16(Wh[0][1][s], bb.v, al0, 0, 0, 0);
        ah1 = __builtin_amdgcn_mfma_f32_16x16x32_bf16(Wh[1][0][s], bb.v, ah1, 0, 0, 0);
        al1 = __builtin_amdgcn_mfma_f32_16x16x32_bf16(Wh[1][1][s], bb.v, al1, 0, 0, 0);
      }
      revalidate16(qa, srcA, (unsigned)(t + 1));
#pragma unroll
      for (int s = 0; s < 4; ++s) {
        union { unsigned u[4]; bf16x8 v; } bb;
#pragma unroll
        for (int j = 0; j < 4; ++j) bb.u[j] = (unsigned)qa[s * 4 + j];
        ah0 = __builtin_amdgcn_mfma_f32_16x16x32_bf16(Wi[0][0][s], bb.v, ah0, 0, 0, 0);
        al0 = __builtin_amdgcn_mfma_f32_16x16x32_bf16(Wi[0][1][s], bb.v, al0, 0, 0, 0);
        ah1 = __builtin_amdgcn_mfma_f32_16x16x32_bf16(Wi[1][0][s], bb.v, ah1, 0, 0, 0);
        al1 = __builtin_amdgcn_mfma_f32_16x16x32_bf16(Wi[1][1][s], bb.v, al1, 0, 0, 0);
      }
    }
    f32x4 am0 = ah0 + al0, am1 = ah1 + al1;
#pragma unroll
    for (int rr = 0; rr < 4; ++rr) {
      pbuf[wid][hi * 4 + rr][b16] = am0[rr];
      pbuf[wid][16 + hi * 4 + rr][b16] = am1[rr];
    }
    __syncthreads();

    // ---- epilogue: wave0 (64 lanes = 16 batches x 4 local cols; 2 tiles each) ----
    if (wid == 0) {
      float hn[2];
#pragma unroll
      for (int m = 0; m < 2; ++m) {
        float pre[4];
#pragma unroll
        for (int q = 0; q < 4; ++q) {
          const int rl = m * 16 + q * 4 + ehl;
          pre[q] = bq[m][q] + gxr[m][q] + pbuf[0][rl][eb] + pbuf[1][rl][eb] +
                   pbuf[2][rl][eb] + pbuf[3][rl][eb];
        }
        float iv = sigf(pre[0]), fv = sigf(pre[1]);
        float gv = tanhf(pre[2]), ov = sigf(pre[3]);
        float& cm = m ? c1 : c0;
        cm = fv * cm + iv * gv;
        hn[m] = ov * tanhf(cm);
      }
      __hip_bfloat16 h0b = __float2bfloat16(hn[0]), h1b = __float2bfloat16(hn[1]);
      int hb0 = (int)*(unsigned short*)&h0b, hb1 = (int)*(unsigned short*)&h1b;
      int pr0 = __shfl_xor(hb0, 16, 64), pr1 = __shfl_xor(hb1, 16, 64);
      unsigned d0 = (unsigned)(unsigned short)hb0 | ((unsigned)(unsigned short)pr0 << 16);
      unsigned d1 = (unsigned)(unsigned short)hb1 | ((unsigned)(unsigned short)pr1 << 16);
      unsigned d0o = (unsigned)__shfl((int)d0, eb + 32, 64);  // tile0 cols 2,3
      unsigned d1o = (unsigned)__shfl((int)d1, eb + 32, 64);  // tile1 cols 6,7
      u64 tagw = (u64)(unsigned)(t + 1) << 32;
      u64* ringo = (lay ? h1r : h0r) + (size_t)(t + 1) * 4096;
      if ((ehl & 1) == 0) {
        agstore(ringo + ((r * 4 + (ehl >> 1)) * 16 + eb), (u64)d0 | tagw);
        agstore(ringo + ((r * 4 + 2 + (ehl >> 1)) * 16 + eb), (u64)d1 | tagw);
      }
      if (lay && ehl == 0) {
        uint4 ov4 = {d0, d0o, d1, d1o};  // cols 0..7
        *(uint4*)(outs + ((size_t)(t * 16 + eb)) * 512 + hc0) = ov4;
      }
    }
    __syncthreads();  // pbuf reuse guard
  }
}

// ---------------- FC GEMM: out[b][t][32000] = outs[t*16+b][:] @ fcw^T + fcb ----------------
__global__ __launch_bounds__(256) void fc_gemm(const __hip_bfloat16* __restrict__ A,
                                               const __hip_bfloat16* __restrict__ Bw,
                                               const float* __restrict__ bias,
                                               float* __restrict__ C) {
  __shared__ __align__(16) unsigned short lds_a[128 * 32];
  __shared__ __align__(16) unsigned short lds_b[128 * 32];
  const int tid = threadIdx.x;
  const int lane = tid & 63, wid = tid >> 6;
  const int m0 = blockIdx.y * 128, n0 = blockIdx.x * 128;
  const char* Ab = (const char*)A;
  const char* Bb = (const char*)Bw;
  const int ra = tid >> 2, cb = (tid & 3) * 16;
  f32x4 acc[4][4] = {};
  const int wm = (wid >> 1) * 64, wn = (wid & 1) * 64;
  const int fr = lane & 15, fk = (lane >> 4) * 8;
  for (int k0 = 0; k0 < HID; k0 += 32) {
    ld_lds16(Ab + (size_t)(m0 + ra) * 1024 + k0 * 2 + cb, (char*)lds_a + wid * 1024);
    ld_lds16(Ab + (size_t)(m0 + 64 + ra) * 1024 + k0 * 2 + cb, (char*)lds_a + 4096 + wid * 1024);
    ld_lds16(Bb + (size_t)(n0 + ra) * 1024 + k0 * 2 + cb, (char*)lds_b + wid * 1024);
    ld_lds16(Bb + (size_t)(n0 + 64 + ra) * 1024 + k0 * 2 + cb, (char*)lds_b + 4096 + wid * 1024);
    __syncthreads();
    bf16x8 af[4], bf[4];
#pragma unroll
    for (int i = 0; i < 4; ++i) af[i] = *(const bf16x8*)&lds_a[(wm + i * 16 + fr) * 32 + fk];
#pragma unroll
    for (int j = 0; j < 4; ++j) bf[j] = *(const bf16x8*)&lds_b[(wn + j * 16 + fr) * 32 + fk];
#pragma unroll
    for (int i = 0; i < 4; ++i)
#pragma unroll
      for (int j = 0; j < 4; ++j)
        acc[i][j] = __builtin_amdgcn_mfma_f32_16x16x32_bf16(af[i], bf[j], acc[i][j], 0, 0, 0);
    __syncthreads();
  }
  const int cr = (lane >> 4) * 4, cc = lane & 15;
  float bv[4];
#pragma unroll
  for (int jj = 0; jj < 4; ++jj) bv[jj] = bias[n0 + wn + jj * 16 + cc];
#pragma unroll
  for (int i = 0; i < 4; ++i) {
#pragma unroll
    for (int jj = 0; jj < 4; ++jj) {
#pragma unroll
      for (int rr = 0; rr < 4; ++rr) {
        int tok = m0 + wm + i * 16 + cr + rr;      // = t*16 + b
        int orow = (tok & 15) * SEQ + (tok >> 4);  // = b*256 + t
        C[(size_t)orow * VOC + (n0 + wn + jj * 16 + cc)] = acc[i][jj][rr] + bv[jj];
      }
    }
  }
}

extern "C" void kernel_launch(void* const* d_in, const int* in_sizes, int n_in,
                              void* d_out, int out_size, void* d_ws, size_t ws_size,
                              hipStream_t stream) {
  const int* x = (const int*)d_in[0];
  const float* emb = (const float*)d_in[1];
  const float* Wih = (const float*)d_in[2];
  const float* Whh = (const float*)d_in[3];
  const float* bias = (const float*)d_in[4];
  const float* fcw = (const float*)d_in[5];
  const float* fcb = (const float*)d_in[6];
  float* out = (float*)d_out;
  char* ws = (char*)d_ws;

  // ws layout (bytes), total 39,911,424:
  //   [0, 8421376)           h0 ring: 257 slots x 32KB (u64 = 2 bf16 cols + tag)
  //   [8421376, 16842752)    h1 ring: 257 slots x 32KB
  //   [16842752, 18939904)   wih0 bf16 [2048][512]        (dead after gx_gemm)
  //   [18939904, 35717120)   gx bf16 [4096][2048]         (dead after lstm_k)
  //   [35717120, 39911424)   xe[4096][512] bf16 -> reused as outs after gx_gemm
  //   fcw_bf aliases [0, 32768000) (rings+wih0+gx head), written after lstm_k
  u64* h0r = (u64*)ws;
  u64* h1r = (u64*)(ws + 8421376);
  uint4* wih0_bf = (uint4*)(ws + 16842752);
  unsigned short* gxb = (unsigned short*)(ws + 18939904);
  unsigned short* xe = (unsigned short*)(ws + 35717120);
  unsigned short* outs = (unsigned short*)(ws + 35717120);
  uint4* fcw_bf = (uint4*)ws;

  hipMemsetAsync(ws, 0, 16842752, stream);  // both rings: tags=0 (slot0 = valid zero h[-1])
  embed_k<<<SEQ * NB, 64, 0, stream>>>(x, emb, xe);
  cvt_k<<<512, 256, 0, stream>>>(Wih, wih0_bf);  // layer-0 Wih (1M elems)
  gx_gemm<<<dim3(16, 32), 256, 0, stream>>>((const __hip_bfloat16*)xe,
                                            (const __hip_bfloat16*)wih0_bf, gxb);
  lstm_k<<<128, 256, 0, stream>>>(Wih, Whh, bias, gxb, h0r, h1r, outs);
  cvt_k<<<8000, 256, 0, stream>>>(fcw, fcw_bf);  // aliases rings/gx (dead after lstm)
  fc_gemm<<<dim3(250, 32), 256, 0, stream>>>((const __hip_bfloat16*)outs,
                                             (const __hip_bfloat16*)fcw_bf, fcb, out);
}

// Round 9
// 1282.315 us; speedup vs baseline: 1.1296x; 1.1296x over previous
//
#include <hip/hip_runtime.h>
#include <hip/hip_bf16.h>

#define SEQ 256
#define NB 16
#define HID 512
#define VOC 32000

typedef short bf16x8 __attribute__((ext_vector_type(8)));
typedef float f32x4 __attribute__((ext_vector_type(4)));
typedef unsigned long long u64;

__device__ __forceinline__ void ld_lds16(const void* g, void* l) {
  __builtin_amdgcn_global_load_lds((const __attribute__((address_space(1))) void*)g,
                                   (__attribute__((address_space(3))) void*)l, 16, 0, 0);
}

__device__ __forceinline__ float sigf(float x) { return 1.0f / (1.0f + expf(-x)); }

__device__ __forceinline__ unsigned pk2(float a, float b) {
  __hip_bfloat16 ha = __float2bfloat16(a), hb = __float2bfloat16(b);
  unsigned short ua = *(unsigned short*)&ha, ub = *(unsigned short*)&hb;
  return (unsigned)ua | ((unsigned)ub << 16);
}

__device__ __forceinline__ u64 agload(const u64* p) {
  return __hip_atomic_load(p, __ATOMIC_RELAXED, __HIP_MEMORY_SCOPE_AGENT);
}
__device__ __forceinline__ void agstore(u64* p, u64 v) {
  __hip_atomic_store(p, v, __ATOMIC_RELAXED, __HIP_MEMORY_SCOPE_AGENT);
}

// N staging u64s per lane: u64 idx = lbase + (i>>2)*256 + (i&3)*16
template <int N>
__device__ __forceinline__ void issueN(u64* q, const u64* base) {
#pragma unroll
  for (int i = 0; i < N; ++i) q[i] = agload(base + (i >> 2) * 256 + (i & 3) * 16);
}
// R7-style parallel-round revalidate (sentinel variant refuted in R8)
template <int N>
__device__ __forceinline__ void revalN(u64* q, const u64* base, unsigned tg) {
  for (;;) {
    int bad = 0;
#pragma unroll
    for (int i = 0; i < N; ++i) bad |= ((unsigned)(q[i] >> 32) != tg);
    if (!__any(bad)) break;
    __builtin_amdgcn_s_sleep(1);
#pragma unroll
    for (int i = 0; i < N; ++i)
      if ((unsigned)(q[i] >> 32) != tg) q[i] = agload(base + (i >> 2) * 256 + (i & 3) * 16);
  }
}

// 8 f32 -> bf16 hi + bf16 lo(residual)
__device__ __forceinline__ void cvt8_hilo(const float* p, bf16x8* h8, bf16x8* l8) {
  union { unsigned short u[8]; bf16x8 v; } uh, ul;
#pragma unroll
  for (int i = 0; i < 8; ++i) {
    float v = p[i];
    __hip_bfloat16 h = __float2bfloat16(v);
    uh.u[i] = *(unsigned short*)&h;
    float rem = v - __bfloat162float(h);
    __hip_bfloat16 l = __float2bfloat16(rem);
    ul.u[i] = *(unsigned short*)&l;
  }
  *h8 = uh.v;
  *l8 = ul.v;
}

// ---------------- embedding gather -> bf16, xe[t*16+b][512] ----------------
__global__ void embed_k(const int* __restrict__ x, const float* __restrict__ emb,
                        unsigned short* __restrict__ xe) {
  int bid = blockIdx.x;  // = t*16 + b
  int t = bid >> 4, b = bid & 15;
  int tok = x[b * SEQ + t];
  const float4* src = (const float4*)(emb + (size_t)tok * HID);
  int e = threadIdx.x;
  float4 a = src[e * 2], c = src[e * 2 + 1];
  uint4 o;
  o.x = pk2(a.x, a.y); o.y = pk2(a.z, a.w);
  o.z = pk2(c.x, c.y); o.w = pk2(c.z, c.w);
  ((uint4*)(xe + (size_t)bid * HID))[e] = o;
}

// ---------------- f32 -> bf16 pack, 8/thread ----------------
__global__ void cvt_k(const float* __restrict__ in, uint4* __restrict__ out) {
  size_t i = (size_t)blockIdx.x * blockDim.x + threadIdx.x;
  const float4* in4 = (const float4*)in;
  float4 a = in4[i * 2], b = in4[i * 2 + 1];
  uint4 o;
  o.x = pk2(a.x, a.y); o.y = pk2(a.z, a.w);
  o.z = pk2(b.x, b.y); o.w = pk2(b.z, b.w);
  out[i] = o;
}

// ---------------- gx GEMM: gx[4096][2048] bf16 = xe @ Wih0^T ----------------
__global__ __launch_bounds__(256) void gx_gemm(const __hip_bfloat16* __restrict__ A,
                                               const __hip_bfloat16* __restrict__ Bw,
                                               unsigned short* __restrict__ C) {
  __shared__ __align__(16) unsigned short lds_a[128 * 32];
  __shared__ __align__(16) unsigned short lds_b[128 * 32];
  const int tid = threadIdx.x;
  const int lane = tid & 63, wid = tid >> 6;
  const int m0 = blockIdx.y * 128, n0 = blockIdx.x * 128;
  const char* Ab = (const char*)A;
  const char* Bb = (const char*)Bw;
  const int ra = tid >> 2, cb = (tid & 3) * 16;
  f32x4 acc[4][4] = {};
  const int wm = (wid >> 1) * 64, wn = (wid & 1) * 64;
  const int fr = lane & 15, fk = (lane >> 4) * 8;
  for (int k0 = 0; k0 < HID; k0 += 32) {
    ld_lds16(Ab + (size_t)(m0 + ra) * 1024 + k0 * 2 + cb, (char*)lds_a + wid * 1024);
    ld_lds16(Ab + (size_t)(m0 + 64 + ra) * 1024 + k0 * 2 + cb, (char*)lds_a + 4096 + wid * 1024);
    ld_lds16(Bb + (size_t)(n0 + ra) * 1024 + k0 * 2 + cb, (char*)lds_b + wid * 1024);
    ld_lds16(Bb + (size_t)(n0 + 64 + ra) * 1024 + k0 * 2 + cb, (char*)lds_b + 4096 + wid * 1024);
    __syncthreads();
    bf16x8 af[4], bf[4];
#pragma unroll
    for (int i = 0; i < 4; ++i) af[i] = *(const bf16x8*)&lds_a[(wm + i * 16 + fr) * 32 + fk];
#pragma unroll
    for (int j = 0; j < 4; ++j) bf[j] = *(const bf16x8*)&lds_b[(wn + j * 16 + fr) * 32 + fk];
#pragma unroll
    for (int i = 0; i < 4; ++i)
#pragma unroll
      for (int j = 0; j < 4; ++j)
        acc[i][j] = __builtin_amdgcn_mfma_f32_16x16x32_bf16(af[i], bf[j], acc[i][j], 0, 0, 0);
    __syncthreads();
  }
  const int cr = (lane >> 4) * 4, cc = lane & 15;
#pragma unroll
  for (int i = 0; i < 4; ++i)
#pragma unroll
    for (int jj = 0; jj < 4; ++jj) {
      size_t base = (size_t)(m0 + wm + i * 16 + cr) * 2048 + (n0 + wn + jj * 16 + cc);
#pragma unroll
      for (int r = 0; r < 4; ++r) {
        __hip_bfloat16 h = __float2bfloat16(acc[i][jj][r]);
        C[base + (size_t)r * 2048] = *(unsigned short*)&h;
      }
    }
}

// ---------------- persistent LSTM: XCD-pinned layers ----------------
// bid%8==0 -> layer 0 (XCD 0), bid%8==1 -> layer 1 (XCD 1), others exit.
// 32 blocks/layer x 512 threads (8 waves). Block owns 16 h-cols (hc0 = r*16):
// 64 gate rows = 4 MFMA tiles (tile m: cols hc0+m*4..+3 x 4 gates), weights reg-resident hi/lo.
// lay0: wave wv covers data-K slice [wv*64,+64) of h0[t-1]; x-part precomputed (gx).
// lay1: waves 0-3 Wih x h0[t] (K-slice [wv*128,+128)); waves 4-7 Whh x h1[t-1].
// 8-wave pbuf reduce; waves 0-3 do epilogue (wave w -> cols hc0+w*4..+3).
// h handoff: u64 = {2 bf16 cols, tag=t+1}, relaxed agent store; consumer revalidates.
__global__ __launch_bounds__(512, 1) void lstm_k(
    const float* __restrict__ Wih, const float* __restrict__ Whh,
    const float* __restrict__ bias, const unsigned short* __restrict__ gxb,
    u64* __restrict__ h0r, u64* __restrict__ h1r, unsigned short* __restrict__ outs) {
  const int bid = blockIdx.x;
  const int sel = bid & 7;
  if (sel > 1) return;
  const int lay = sel, r = bid >> 3;  // r in [0,32)
  const int hc0 = r * 16;
  const int tid = threadIdx.x;
  const int wv = tid >> 6, lane = tid & 63;
  const int b16 = lane & 15, hi = lane >> 4;
  __shared__ float pbuf[8][64][17];  // 34.8 KB

  // ---- weights -> registers (A-frag: row = lane&15 within tile, k = slice + s*32 + hi*8) ----
  bf16x8 W[4][2][4];  // [tile][hi/lo][s]; lay0 uses s 0..1 only
  {
    const int q = b16 >> 2, c = b16 & 3;
    if (lay == 0) {
#pragma unroll
      for (int m = 0; m < 4; ++m) {
        const float* row = Whh + (size_t)(q * HID + hc0 + m * 4 + c) * HID;
#pragma unroll
        for (int s = 0; s < 2; ++s)
          cvt8_hilo(row + wv * 64 + s * 32 + hi * 8, &W[m][0][s], &W[m][1][s]);
      }
    } else {
      const float* basep = (wv < 4) ? Wih : Whh;
      const int kb = (wv & 3) * 128;
#pragma unroll
      for (int m = 0; m < 4; ++m) {
        const float* row = basep + (size_t)(2048 + q * HID + hc0 + m * 4 + c) * HID;
#pragma unroll
        for (int s = 0; s < 4; ++s)
          cvt8_hilo(row + kb + s * 32 + hi * 8, &W[m][0][s], &W[m][1][s]);
      }
    }
  }
  const int eb = b16, ehl = hi;  // epilogue mapping: wave wv<4 -> (batch eb, col hc0+wv*4+ehl)
  const bool epi = (wv < 4);
  float bq[4];
  if (epi) {
#pragma unroll
    for (int q = 0; q < 4; ++q) bq[q] = bias[lay * 2048 + q * HID + hc0 + wv * 4 + ehl];
  }
  float c_reg = 0.f;

#pragma unroll 1
  for (int t = 0; t < SEQ; ++t) {
    f32x4 acc[4] = {{0.f, 0.f, 0.f, 0.f}, {0.f, 0.f, 0.f, 0.f},
                    {0.f, 0.f, 0.f, 0.f}, {0.f, 0.f, 0.f, 0.f}};
    float gxr[4] = {0.f, 0.f, 0.f, 0.f};
    if (lay == 0) {
      const u64* src = h0r + (size_t)t * 4096 + (wv * 512 + hi * 64 + b16);  // h0[t-1], tag t
      u64 q8[8];
      issueN<8>(q8, src);
      if (epi) {
        const unsigned short* gp = gxb + ((size_t)(t * 16 + eb)) * 2048 + hc0 + wv * 4 + ehl;
#pragma unroll
        for (int q = 0; q < 4; ++q) {
          union { unsigned u; float f; } cv;
          cv.u = (unsigned)gp[q * HID] << 16;
          gxr[q] = cv.f;
          asm volatile("" : "+v"(gxr[q]));
        }
      }
      revalN<8>(q8, src, (unsigned)t);
#pragma unroll
      for (int s = 0; s < 2; ++s) {
        union { unsigned u[4]; bf16x8 v; } bb;
#pragma unroll
        for (int j = 0; j < 4; ++j) bb.u[j] = (unsigned)q8[s * 4 + j];
#pragma unroll
        for (int m = 0; m < 4; ++m) {
          acc[m] = __builtin_amdgcn_mfma_f32_16x16x32_bf16(W[m][0][s], bb.v, acc[m], 0, 0, 0);
          acc[m] = __builtin_amdgcn_mfma_f32_16x16x32_bf16(W[m][1][s], bb.v, acc[m], 0, 0, 0);
        }
      }
    } else {
      const u64* src = ((wv < 4) ? (h0r + (size_t)(t + 1) * 4096)   // h0[t], tag t+1
                                 : (h1r + (size_t)t * 4096))        // h1[t-1], tag t
                       + ((wv & 3) * 1024 + hi * 64 + b16);
      const unsigned tg = (wv < 4) ? (unsigned)(t + 1) : (unsigned)t;
      u64 q16[16];
      issueN<16>(q16, src);
      revalN<16>(q16, src, tg);
#pragma unroll
      for (int s = 0; s < 4; ++s) {
        union { unsigned u[4]; bf16x8 v; } bb;
#pragma unroll
        for (int j = 0; j < 4; ++j) bb.u[j] = (unsigned)q16[s * 4 + j];
#pragma unroll
        for (int m = 0; m < 4; ++m) {
          acc[m] = __builtin_amdgcn_mfma_f32_16x16x32_bf16(W[m][0][s], bb.v, acc[m], 0, 0, 0);
          acc[m] = __builtin_amdgcn_mfma_f32_16x16x32_bf16(W[m][1][s], bb.v, acc[m], 0, 0, 0);
        }
      }
    }
#pragma unroll
    for (int m = 0; m < 4; ++m)
#pragma unroll
      for (int rr = 0; rr < 4; ++rr) pbuf[wv][m * 16 + hi * 4 + rr][b16] = acc[m][rr];
    __syncthreads();

    // ---- epilogue: waves 0-3 (wave w -> cols hc0+w*4..+3; lane = (batch, local col)) ----
    if (epi) {
      float pre[4];
#pragma unroll
      for (int q = 0; q < 4; ++q) {
        const int rl = wv * 16 + q * 4 + ehl;
        float s0 = pbuf[0][rl][eb] + pbuf[1][rl][eb] + pbuf[2][rl][eb] + pbuf[3][rl][eb];
        float s1 = pbuf[4][rl][eb] + pbuf[5][rl][eb] + pbuf[6][rl][eb] + pbuf[7][rl][eb];
        pre[q] = bq[q] + gxr[q] + s0 + s1;
      }
      float iv = sigf(pre[0]), fv = sigf(pre[1]);
      float gv = tanhf(pre[2]), ov = sigf(pre[3]);
      c_reg = fv * c_reg + iv * gv;
      float hn = ov * tanhf(c_reg);
      __hip_bfloat16 hh = __float2bfloat16(hn);
      int hb = (int)*(unsigned short*)&hh;
      int pr = __shfl_xor(hb, 16, 64);  // col ^ 1 partner
      unsigned data32 = (unsigned)(unsigned short)hb | ((unsigned)(unsigned short)pr << 16);
      u64 tagw = (u64)(unsigned)(t + 1) << 32;
      u64* ringo = (lay ? h1r : h0r) + (size_t)(t + 1) * 4096;
      if ((ehl & 1) == 0) {
        const int cp = r * 8 + wv * 2 + (ehl >> 1);  // colpair
        agstore(ringo + cp * 16 + eb, (u64)data32 | tagw);
      }
      if (lay) {
        unsigned d2 = (unsigned)__shfl((int)data32, eb + 32, 64);  // cols +2,+3 (ehl=2 lane)
        if (ehl == 0)
          *(u64*)(outs + ((size_t)(t * 16 + eb)) * 512 + hc0 + wv * 4) =
              (u64)data32 | ((u64)d2 << 32);
      }
    }
    __syncthreads();  // pbuf reuse guard
  }
}

// ---------------- FC GEMM: out[b][t][32000] = outs[t*16+b][:] @ fcw^T + fcb ----------------
__global__ __launch_bounds__(256) void fc_gemm(const __hip_bfloat16* __restrict__ A,
                                               const __hip_bfloat16* __restrict__ Bw,
                                               const float* __restrict__ bias,
                                               float* __restrict__ C) {
  __shared__ __align__(16) unsigned short lds_a[128 * 32];
  __shared__ __align__(16) unsigned short lds_b[128 * 32];
  const int tid = threadIdx.x;
  const int lane = tid & 63, wid = tid >> 6;
  const int m0 = blockIdx.y * 128, n0 = blockIdx.x * 128;
  const char* Ab = (const char*)A;
  const char* Bb = (const char*)Bw;
  const int ra = tid >> 2, cb = (tid & 3) * 16;
  f32x4 acc[4][4] = {};
  const int wm = (wid >> 1) * 64, wn = (wid & 1) * 64;
  const int fr = lane & 15, fk = (lane >> 4) * 8;
  for (int k0 = 0; k0 < HID; k0 += 32) {
    ld_lds16(Ab + (size_t)(m0 + ra) * 1024 + k0 * 2 + cb, (char*)lds_a + wid * 1024);
    ld_lds16(Ab + (size_t)(m0 + 64 + ra) * 1024 + k0 * 2 + cb, (char*)lds_a + 4096 + wid * 1024);
    ld_lds16(Bb + (size_t)(n0 + ra) * 1024 + k0 * 2 + cb, (char*)lds_b + wid * 1024);
    ld_lds16(Bb + (size_t)(n0 + 64 + ra) * 1024 + k0 * 2 + cb, (char*)lds_b + 4096 + wid * 1024);
    __syncthreads();
    bf16x8 af[4], bf[4];
#pragma unroll
    for (int i = 0; i < 4; ++i) af[i] = *(const bf16x8*)&lds_a[(wm + i * 16 + fr) * 32 + fk];
#pragma unroll
    for (int j = 0; j < 4; ++j) bf[j] = *(const bf16x8*)&lds_b[(wn + j * 16 + fr) * 32 + fk];
#pragma unroll
    for (int i = 0; i < 4; ++i)
#pragma unroll
      for (int j = 0; j < 4; ++j)
        acc[i][j] = __builtin_amdgcn_mfma_f32_16x16x32_bf16(af[i], bf[j], acc[i][j], 0, 0, 0);
    __syncthreads();
  }
  const int cr = (lane >> 4) * 4, cc = lane & 15;
  float bv[4];
#pragma unroll
  for (int jj = 0; jj < 4; ++jj) bv[jj] = bias[n0 + wn + jj * 16 + cc];
#pragma unroll
  for (int i = 0; i < 4; ++i) {
#pragma unroll
    for (int jj = 0; jj < 4; ++jj) {
#pragma unroll
      for (int rr = 0; rr < 4; ++rr) {
        int tok = m0 + wm + i * 16 + cr + rr;      // = t*16 + b
        int orow = (tok & 15) * SEQ + (tok >> 4);  // = b*256 + t
        C[(size_t)orow * VOC + (n0 + wn + jj * 16 + cc)] = acc[i][jj][rr] + bv[jj];
      }
    }
  }
}

extern "C" void kernel_launch(void* const* d_in, const int* in_sizes, int n_in,
                              void* d_out, int out_size, void* d_ws, size_t ws_size,
                              hipStream_t stream) {
  const int* x = (const int*)d_in[0];
  const float* emb = (const float*)d_in[1];
  const float* Wih = (const float*)d_in[2];
  const float* Whh = (const float*)d_in[3];
  const float* bias = (const float*)d_in[4];
  const float* fcw = (const float*)d_in[5];
  const float* fcb = (const float*)d_in[6];
  float* out = (float*)d_out;
  char* ws = (char*)d_ws;

  // ws layout (bytes), total 39,911,424:
  //   [0, 8421376)           h0 ring: 257 slots x 32KB (u64 = 2 bf16 cols + tag)
  //   [8421376, 16842752)    h1 ring: 257 slots x 32KB
  //   [16842752, 18939904)   wih0 bf16 [2048][512]        (dead after gx_gemm)
  //   [18939904, 35717120)   gx bf16 [4096][2048]         (dead after lstm_k)
  //   [35717120, 39911424)   xe[4096][512] bf16 -> reused as outs after gx_gemm
  //   fcw_bf aliases [0, 32768000) (rings+wih0+gx head), written after lstm_k
  u64* h0r = (u64*)ws;
  u64* h1r = (u64*)(ws + 8421376);
  uint4* wih0_bf = (uint4*)(ws + 16842752);
  unsigned short* gxb = (unsigned short*)(ws + 18939904);
  unsigned short* xe = (unsigned short*)(ws + 35717120);
  unsigned short* outs = (unsigned short*)(ws + 35717120);
  uint4* fcw_bf = (uint4*)ws;

  hipMemsetAsync(ws, 0, 16842752, stream);  // both rings: tags=0 (slot0 = valid zero h[-1])
  embed_k<<<SEQ * NB, 64, 0, stream>>>(x, emb, xe);
  cvt_k<<<512, 256, 0, stream>>>(Wih, wih0_bf);  // layer-0 Wih (1M elems)
  gx_gemm<<<dim3(16, 32), 256, 0, stream>>>((const __hip_bfloat16*)xe,
                                            (const __hip_bfloat16*)wih0_bf, gxb);
  lstm_k<<<256, 512, 0, stream>>>(Wih, Whh, bias, gxb, h0r, h1r, outs);
  cvt_k<<<8000, 256, 0, stream>>>(fcw, fcw_bf);  // aliases rings/gx (dead after lstm)
  fc_gemm<<<dim3(250, 32), 256, 0, stream>>>((const __hip_bfloat16*)outs,
                                             (const __hip_bfloat16*)fcw_bf, fcb, out);
}